// Round 2
// baseline (715.902 us; speedup 1.0000x reference)
//
#include <hip/hip_runtime.h>
#include <cstdint>
#include <cstddef>

// ---------------------------------------------------------------------------
// GraphSAGE 3-layer forward, f32.
//   layer: out = mean_aggr(h)[dst] @ W_l + b + h @ W_r ; relu on layers 0,1
// Strategy:
//   1. Build CSR-by-dst on device each launch (hist -> scan -> fill).
//   2. Aggregation: one wave per dst node, float2/lane coalesced row gathers.
//   3. GEMM: 32-row tile in LDS (stride 132 pad), weights from global (L1),
//      register accumulators, f32 vector FMA (no fp32 MFMA on CDNA4).
// NOTE: harness delivers integer inputs as int32 -> edge_index is const int*.
//       (Casting it to long long* was the R1 core-dump: OOB 64-bit reads gave
//       garbage indices -> wild atomics -> GPU memory fault.)
// ---------------------------------------------------------------------------

#define HID 128

// ---- small utility --------------------------------------------------------

__global__ __launch_bounds__(256) void zero_i32_kernel(int* __restrict__ p, int n)
{
    int i = blockIdx.x * 256 + threadIdx.x;
    if (i < n) p[i] = 0;
}

// ---- CSR build ------------------------------------------------------------

__global__ __launch_bounds__(256) void deg_hist_kernel(
    const int* __restrict__ dst, int* __restrict__ deg, int E, int n)
{
    int e = blockIdx.x * 256 + threadIdx.x;
    if (e < E) {
        int d = dst[e];
        if (d >= 0 && d < n) atomicAdd(&deg[d], 1);
    }
}

__global__ __launch_bounds__(1024) void scan_kernel(
    const int* __restrict__ deg, int* __restrict__ offs,
    int* __restrict__ cursor, int n, int total_edges)
{
    __shared__ int part[1024];
    const int t = threadIdx.x;
    const int chunk = (n + 1023) / 1024;
    const int beg = t * chunk;
    const int end = min(beg + chunk, n);
    int s = 0;
    for (int i = beg; i < end; ++i) s += deg[i];
    part[t] = s;
    __syncthreads();
    // Hillis-Steele inclusive scan over 1024 partials
    for (int off = 1; off < 1024; off <<= 1) {
        int v = (t >= off) ? part[t - off] : 0;
        __syncthreads();
        part[t] += v;
        __syncthreads();
    }
    int run = (t == 0) ? 0 : part[t - 1];
    for (int i = beg; i < end; ++i) {
        offs[i] = run;
        cursor[i] = run;
        run += deg[i];
    }
    if (t == 1023) offs[n] = total_edges;
}

__global__ __launch_bounds__(256) void csr_fill_kernel(
    const int* __restrict__ src, const int* __restrict__ dst,
    int* __restrict__ cursor, int* __restrict__ esrc, int E, int n)
{
    int e = blockIdx.x * 256 + threadIdx.x;
    if (e < E) {
        int d = dst[e];
        int s = src[e];
        if (d >= 0 && d < n && s >= 0 && s < n) {
            int p = atomicAdd(&cursor[d], 1);
            esrc[p] = s;
        }
    }
}

// ---- Mean aggregation: one wave (64 lanes) per dst node -------------------
// Each lane owns 2 consecutive floats of the 128-wide row -> 512B coalesced
// read per neighbor row.

__global__ __launch_bounds__(256) void sage_aggregate(
    const float* __restrict__ hin, const int* __restrict__ offs,
    const int* __restrict__ esrc, float* __restrict__ aggr, int n)
{
    const int wid  = threadIdx.x >> 6;
    const int lane = threadIdx.x & 63;
    const int node = blockIdx.x * 4 + wid;
    if (node >= n) return;
    const int beg = offs[node];
    const int end = offs[node + 1];
    float ax = 0.f, ay = 0.f;
    for (int e = beg; e < end; ++e) {
        const int s = esrc[e];   // wave-uniform; cache-broadcast
        const float2 v = *(const float2*)(&hin[(size_t)s * HID + lane * 2]);
        ax += v.x;
        ay += v.y;
    }
    const float inv = 1.0f / fmaxf((float)(end - beg), 1.0f);
    float2 o;
    o.x = ax * inv;
    o.y = ay * inv;
    *(float2*)(&aggr[(size_t)node * HID + lane * 2]) = o;
}

// ---- Dense: out = aggr @ Wl + h @ Wr + b  (optional ReLU) -----------------
// Block: 256 threads, 32-row tile. DOUT=128: 32 colgroups x 8 rowgroups,
// 4 rows/thread. DOUT=64: 16 colgroups x 16 rowgroups, 2 rows/thread.
// aggr/h tiles staged in LDS with +4 pad (stride 132).

template <int DOUT, bool RELU>
__global__ __launch_bounds__(256) void sage_gemm(
    const float* __restrict__ aggr, const float* __restrict__ h,
    const float* __restrict__ Wl, const float* __restrict__ Wr,
    const float* __restrict__ bias, float* __restrict__ out, int n)
{
    constexpr int K    = HID;
    constexpr int CG   = DOUT / 4;     // column groups (4 cols each)
    constexpr int RG   = 256 / CG;     // row groups
    constexpr int RPT  = 32 / RG;      // rows per thread
    constexpr int ROWS = 32;
    constexpr int LDSS = K + 4;        // padded LDS stride

    __shared__ float sA[ROWS * LDSS];
    __shared__ float sH[ROWS * LDSS];

    const int tx   = threadIdx.x;
    const int row0 = blockIdx.x * ROWS;

    // Stage 32x128 tiles of aggr and h (float4 loads, zero-fill past n).
    for (int i = tx; i < ROWS * (K / 4); i += 256) {
        const int r  = i / (K / 4);
        const int c4 = i % (K / 4);
        const int row = row0 + r;
        float4 va = make_float4(0.f, 0.f, 0.f, 0.f);
        float4 vh = va;
        if (row < n) {
            va = ((const float4*)(aggr + (size_t)row * K))[c4];
            vh = ((const float4*)(h    + (size_t)row * K))[c4];
        }
        *(float4*)&sA[r * LDSS + c4 * 4] = va;
        *(float4*)&sH[r * LDSS + c4 * 4] = vh;
    }
    __syncthreads();

    const int cg  = tx % CG;
    const int rg  = tx / CG;
    const int col = cg * 4;

    float acc[RPT][4];
#pragma unroll
    for (int i = 0; i < RPT; ++i)
#pragma unroll
        for (int j = 0; j < 4; ++j) acc[i][j] = 0.f;

#pragma unroll 4
    for (int k = 0; k < K; ++k) {
        const float4 wl = *(const float4*)(&Wl[k * DOUT + col]);
        const float4 wr = *(const float4*)(&Wr[k * DOUT + col]);
#pragma unroll
        for (int i = 0; i < RPT; ++i) {
            const float a  = sA[(rg * RPT + i) * LDSS + k];
            const float hv = sH[(rg * RPT + i) * LDSS + k];
            acc[i][0] = fmaf(a, wl.x, fmaf(hv, wr.x, acc[i][0]));
            acc[i][1] = fmaf(a, wl.y, fmaf(hv, wr.y, acc[i][1]));
            acc[i][2] = fmaf(a, wl.z, fmaf(hv, wr.z, acc[i][2]));
            acc[i][3] = fmaf(a, wl.w, fmaf(hv, wr.w, acc[i][3]));
        }
    }

    const float4 bv = *(const float4*)(&bias[col]);
#pragma unroll
    for (int i = 0; i < RPT; ++i) {
        const int row = row0 + rg * RPT + i;
        if (row < n) {
            float4 o;
            o.x = acc[i][0] + bv.x;
            o.y = acc[i][1] + bv.y;
            o.z = acc[i][2] + bv.z;
            o.w = acc[i][3] + bv.w;
            if (RELU) {
                o.x = fmaxf(o.x, 0.f);
                o.y = fmaxf(o.y, 0.f);
                o.z = fmaxf(o.z, 0.f);
                o.w = fmaxf(o.w, 0.f);
            }
            *(float4*)(&out[(size_t)row * DOUT + col]) = o;
        }
    }
}

// ---------------------------------------------------------------------------

static inline size_t align_up(size_t v, size_t a) { return (v + a - 1) & ~(a - 1); }

extern "C" void kernel_launch(void* const* d_in, const int* in_sizes, int n_in,
                              void* d_out, int out_size, void* d_ws, size_t ws_size,
                              hipStream_t stream)
{
    const float* x   = (const float*)d_in[0];
    const int*   ei  = (const int*)d_in[1];      // int32! (harness converts int64)
    const float* wl0 = (const float*)d_in[2];
    const float* b0  = (const float*)d_in[3];
    const float* wr0 = (const float*)d_in[4];
    const float* wl1 = (const float*)d_in[5];
    const float* b1  = (const float*)d_in[6];
    const float* wr1 = (const float*)d_in[7];
    const float* wl2 = (const float*)d_in[8];
    const float* b2  = (const float*)d_in[9];
    const float* wr2 = (const float*)d_in[10];
    float*       out = (float*)d_out;

    const int N = in_sizes[0] / HID;   // 50000
    const int E = in_sizes[1] / 2;     // 800000
    const int* src = ei;
    const int* dst = ei + E;

    // Workspace carve-up (~80.6 MB total)
    char*  ws  = (char*)d_ws;
    size_t off = 0;
    int* offs   = (int*)(ws + off); off = align_up(off + (size_t)(N + 1) * 4, 256);
    int* cursor = (int*)(ws + off); off = align_up(off + (size_t)N * 4, 256);
    int* deg    = (int*)(ws + off); off = align_up(off + (size_t)N * 4, 256);
    int* esrc   = (int*)(ws + off); off = align_up(off + (size_t)E * 4, 256);
    float* aggr = (float*)(ws + off); off = align_up(off + (size_t)N * HID * 4, 256);
    float* h0   = (float*)(ws + off); off = align_up(off + (size_t)N * HID * 4, 256);
    float* h1   = (float*)(ws + off); off = align_up(off + (size_t)N * HID * 4, 256);
    (void)ws_size; (void)n_in; (void)out_size;

    // --- CSR build (reused by all 3 layers) ---
    zero_i32_kernel<<<(N + 255) / 256, 256, 0, stream>>>(deg, N);
    deg_hist_kernel<<<(E + 255) / 256, 256, 0, stream>>>(dst, deg, E, N);
    scan_kernel<<<1, 1024, 0, stream>>>(deg, offs, cursor, N, E);
    csr_fill_kernel<<<(E + 255) / 256, 256, 0, stream>>>(src, dst, cursor, esrc, E, N);

    const int aggGrid  = (N + 3) / 4;
    const int gemmGrid = (N + 31) / 32;

    // Layer 0: x -> h0 (ReLU)
    sage_aggregate<<<aggGrid, 256, 0, stream>>>(x, offs, esrc, aggr, N);
    sage_gemm<128, true><<<gemmGrid, 256, 0, stream>>>(aggr, x, wl0, wr0, b0, h0, N);

    // Layer 1: h0 -> h1 (ReLU)
    sage_aggregate<<<aggGrid, 256, 0, stream>>>(h0, offs, esrc, aggr, N);
    sage_gemm<128, true><<<gemmGrid, 256, 0, stream>>>(aggr, h0, wl1, wr1, b1, h1, N);

    // Layer 2: h1 -> out (no ReLU)
    sage_aggregate<<<aggGrid, 256, 0, stream>>>(h1, offs, esrc, aggr, N);
    sage_gemm<64, false><<<gemmGrid, 256, 0, stream>>>(aggr, h1, wl2, wr2, b2, out, N);
}

// Round 3
// 613.928 us; speedup vs baseline: 1.1661x; 1.1661x over previous
//
#include <hip/hip_runtime.h>
#include <cstdint>
#include <cstddef>

// ---------------------------------------------------------------------------
// GraphSAGE 3-layer forward, f32.
//   layer: out = mean_aggr(h)[dst] @ W_l + b + h @ W_r ; relu on layers 0,1
// Strategy:
//   1. Build CSR-by-dst on device each launch (hist -> 3-kernel parallel scan
//      -> fill). R2 post-mortem: single-block scan was 110us (latency-bound,
//      1 CU); parallel scan is ~5-10us.
//   2. Aggregation: one wave per dst node, float2/lane coalesced row gathers.
//   3. GEMM: 32-row tile in LDS (stride 132 pad), weights from global (L1),
//      register accumulators, f32 vector FMA (no fp32 MFMA on CDNA4).
// NOTE: harness delivers integer inputs as int32 -> edge_index is const int*.
// ---------------------------------------------------------------------------

#define HID 128
#define SCAN_CHUNK 1024   // deg elements per scan block (256 thr x 4)

// ---- small utility --------------------------------------------------------

__global__ __launch_bounds__(256) void zero_i32_kernel(int* __restrict__ p, int n)
{
    int i = blockIdx.x * 256 + threadIdx.x;
    if (i < n) p[i] = 0;
}

// ---- CSR build ------------------------------------------------------------

__global__ __launch_bounds__(256) void deg_hist_kernel(
    const int* __restrict__ dst, int* __restrict__ deg, int E, int n)
{
    int e = blockIdx.x * 256 + threadIdx.x;
    if (e < E) {
        int d = dst[e];
        if (d >= 0 && d < n) atomicAdd(&deg[d], 1);
    }
}

// partials[b] = sum of deg[b*1024 .. b*1024+1023]
__global__ __launch_bounds__(256) void block_sum_kernel(
    const int* __restrict__ deg, int* __restrict__ partials, int n)
{
    __shared__ int red[256];
    const int base = blockIdx.x * SCAN_CHUNK;
    const int t = threadIdx.x;
    int s = 0;
#pragma unroll
    for (int j = 0; j < 4; ++j) {
        const int idx = base + t * 4 + j;
        s += (idx < n) ? deg[idx] : 0;
    }
    red[t] = s;
    __syncthreads();
    for (int off = 128; off > 0; off >>= 1) {
        if (t < off) red[t] += red[t + off];
        __syncthreads();
    }
    if (t == 0) partials[blockIdx.x] = red[0];
}

// in-place exclusive scan of partials[0..nblk), nblk <= 256
__global__ __launch_bounds__(256) void scan_partials_kernel(
    int* __restrict__ partials, int nblk)
{
    __shared__ int buf[256];
    const int t = threadIdx.x;
    const int v = (t < nblk) ? partials[t] : 0;
    buf[t] = v;
    __syncthreads();
    for (int off = 1; off < 256; off <<= 1) {
        const int u = (t >= off) ? buf[t - off] : 0;
        __syncthreads();
        buf[t] += u;
        __syncthreads();
    }
    if (t < nblk) partials[t] = buf[t] - v;   // exclusive
}

// re-scan each 1024-chunk locally, add block base, write offs + cursor
__global__ __launch_bounds__(256) void scan_write_kernel(
    const int* __restrict__ deg, const int* __restrict__ partials,
    int* __restrict__ offs, int* __restrict__ cursor, int n, int E)
{
    __shared__ int buf[256];
    const int base = blockIdx.x * SCAN_CHUNK;
    const int t = threadIdx.x;
    int loc[4];
    int s = 0;
#pragma unroll
    for (int j = 0; j < 4; ++j) {
        const int idx = base + t * 4 + j;
        const int d = (idx < n) ? deg[idx] : 0;
        loc[j] = s;
        s += d;
    }
    buf[t] = s;
    __syncthreads();
    for (int off = 1; off < 256; off <<= 1) {
        const int u = (t >= off) ? buf[t - off] : 0;
        __syncthreads();
        buf[t] += u;
        __syncthreads();
    }
    const int tbase = partials[blockIdx.x] + ((t == 0) ? 0 : buf[t - 1]);
#pragma unroll
    for (int j = 0; j < 4; ++j) {
        const int idx = base + t * 4 + j;
        if (idx < n) {
            const int o = tbase + loc[j];
            offs[idx] = o;
            cursor[idx] = o;
        }
    }
    if (blockIdx.x == 0 && t == 0) offs[n] = E;
}

__global__ __launch_bounds__(256) void csr_fill_kernel(
    const int* __restrict__ src, const int* __restrict__ dst,
    int* __restrict__ cursor, int* __restrict__ esrc, int E, int n)
{
    int e = blockIdx.x * 256 + threadIdx.x;
    if (e < E) {
        int d = dst[e];
        int s = src[e];
        if (d >= 0 && d < n && s >= 0 && s < n) {
            int p = atomicAdd(&cursor[d], 1);
            esrc[p] = s;
        }
    }
}

// ---- Mean aggregation: one wave (64 lanes) per dst node -------------------
// Each lane owns 2 consecutive floats of the 128-wide row -> 512B coalesced
// read per neighbor row.

__global__ __launch_bounds__(256) void sage_aggregate(
    const float* __restrict__ hin, const int* __restrict__ offs,
    const int* __restrict__ esrc, float* __restrict__ aggr, int n)
{
    const int wid  = threadIdx.x >> 6;
    const int lane = threadIdx.x & 63;
    const int node = blockIdx.x * 4 + wid;
    if (node >= n) return;
    const int beg = offs[node];
    const int end = offs[node + 1];
    float ax = 0.f, ay = 0.f;
    for (int e = beg; e < end; ++e) {
        const int s = esrc[e];   // wave-uniform; cache-broadcast
        const float2 v = *(const float2*)(&hin[(size_t)s * HID + lane * 2]);
        ax += v.x;
        ay += v.y;
    }
    const float inv = 1.0f / fmaxf((float)(end - beg), 1.0f);
    float2 o;
    o.x = ax * inv;
    o.y = ay * inv;
    *(float2*)(&aggr[(size_t)node * HID + lane * 2]) = o;
}

// ---- Dense: out = aggr @ Wl + h @ Wr + b  (optional ReLU) -----------------

template <int DOUT, bool RELU>
__global__ __launch_bounds__(256) void sage_gemm(
    const float* __restrict__ aggr, const float* __restrict__ h,
    const float* __restrict__ Wl, const float* __restrict__ Wr,
    const float* __restrict__ bias, float* __restrict__ out, int n)
{
    constexpr int K    = HID;
    constexpr int CG   = DOUT / 4;     // column groups (4 cols each)
    constexpr int RG   = 256 / CG;     // row groups
    constexpr int RPT  = 32 / RG;      // rows per thread
    constexpr int ROWS = 32;
    constexpr int LDSS = K + 4;        // padded LDS stride

    __shared__ float sA[ROWS * LDSS];
    __shared__ float sH[ROWS * LDSS];

    const int tx   = threadIdx.x;
    const int row0 = blockIdx.x * ROWS;

    // Stage 32x128 tiles of aggr and h (float4 loads, zero-fill past n).
    for (int i = tx; i < ROWS * (K / 4); i += 256) {
        const int r  = i / (K / 4);
        const int c4 = i % (K / 4);
        const int row = row0 + r;
        float4 va = make_float4(0.f, 0.f, 0.f, 0.f);
        float4 vh = va;
        if (row < n) {
            va = ((const float4*)(aggr + (size_t)row * K))[c4];
            vh = ((const float4*)(h    + (size_t)row * K))[c4];
        }
        *(float4*)&sA[r * LDSS + c4 * 4] = va;
        *(float4*)&sH[r * LDSS + c4 * 4] = vh;
    }
    __syncthreads();

    const int cg  = tx % CG;
    const int rg  = tx / CG;
    const int col = cg * 4;

    float acc[RPT][4];
#pragma unroll
    for (int i = 0; i < RPT; ++i)
#pragma unroll
        for (int j = 0; j < 4; ++j) acc[i][j] = 0.f;

#pragma unroll 4
    for (int k = 0; k < K; ++k) {
        const float4 wl = *(const float4*)(&Wl[k * DOUT + col]);
        const float4 wr = *(const float4*)(&Wr[k * DOUT + col]);
#pragma unroll
        for (int i = 0; i < RPT; ++i) {
            const float a  = sA[(rg * RPT + i) * LDSS + k];
            const float hv = sH[(rg * RPT + i) * LDSS + k];
            acc[i][0] = fmaf(a, wl.x, fmaf(hv, wr.x, acc[i][0]));
            acc[i][1] = fmaf(a, wl.y, fmaf(hv, wr.y, acc[i][1]));
            acc[i][2] = fmaf(a, wl.z, fmaf(hv, wr.z, acc[i][2]));
            acc[i][3] = fmaf(a, wl.w, fmaf(hv, wr.w, acc[i][3]));
        }
    }

    const float4 bv = *(const float4*)(&bias[col]);
#pragma unroll
    for (int i = 0; i < RPT; ++i) {
        const int row = row0 + rg * RPT + i;
        if (row < n) {
            float4 o;
            o.x = acc[i][0] + bv.x;
            o.y = acc[i][1] + bv.y;
            o.z = acc[i][2] + bv.z;
            o.w = acc[i][3] + bv.w;
            if (RELU) {
                o.x = fmaxf(o.x, 0.f);
                o.y = fmaxf(o.y, 0.f);
                o.z = fmaxf(o.z, 0.f);
                o.w = fmaxf(o.w, 0.f);
            }
            *(float4*)(&out[(size_t)row * DOUT + col]) = o;
        }
    }
}

// ---------------------------------------------------------------------------

static inline size_t align_up(size_t v, size_t a) { return (v + a - 1) & ~(a - 1); }

extern "C" void kernel_launch(void* const* d_in, const int* in_sizes, int n_in,
                              void* d_out, int out_size, void* d_ws, size_t ws_size,
                              hipStream_t stream)
{
    const float* x   = (const float*)d_in[0];
    const int*   ei  = (const int*)d_in[1];      // int32! (harness converts int64)
    const float* wl0 = (const float*)d_in[2];
    const float* b0  = (const float*)d_in[3];
    const float* wr0 = (const float*)d_in[4];
    const float* wl1 = (const float*)d_in[5];
    const float* b1  = (const float*)d_in[6];
    const float* wr1 = (const float*)d_in[7];
    const float* wl2 = (const float*)d_in[8];
    const float* b2  = (const float*)d_in[9];
    const float* wr2 = (const float*)d_in[10];
    float*       out = (float*)d_out;

    const int N = in_sizes[0] / HID;   // 50000
    const int E = in_sizes[1] / 2;     // 800000
    const int* src = ei;
    const int* dst = ei + E;

    // Workspace carve-up (~80.6 MB total)
    char*  ws  = (char*)d_ws;
    size_t off = 0;
    int* offs     = (int*)(ws + off); off = align_up(off + (size_t)(N + 1) * 4, 256);
    int* cursor   = (int*)(ws + off); off = align_up(off + (size_t)N * 4, 256);
    int* deg      = (int*)(ws + off); off = align_up(off + (size_t)N * 4, 256);
    int* partials = (int*)(ws + off); off = align_up(off + 256 * 4, 256);
    int* esrc     = (int*)(ws + off); off = align_up(off + (size_t)E * 4, 256);
    float* aggr   = (float*)(ws + off); off = align_up(off + (size_t)N * HID * 4, 256);
    float* h0     = (float*)(ws + off); off = align_up(off + (size_t)N * HID * 4, 256);
    float* h1     = (float*)(ws + off); off = align_up(off + (size_t)N * HID * 4, 256);
    (void)ws_size; (void)n_in; (void)out_size;

    const int nScanBlk = (N + SCAN_CHUNK - 1) / SCAN_CHUNK;   // 49

    // --- CSR build (reused by all 3 layers) ---
    zero_i32_kernel<<<(N + 255) / 256, 256, 0, stream>>>(deg, N);
    deg_hist_kernel<<<(E + 255) / 256, 256, 0, stream>>>(dst, deg, E, N);
    block_sum_kernel<<<nScanBlk, 256, 0, stream>>>(deg, partials, N);
    scan_partials_kernel<<<1, 256, 0, stream>>>(partials, nScanBlk);
    scan_write_kernel<<<nScanBlk, 256, 0, stream>>>(deg, partials, offs, cursor, N, E);
    csr_fill_kernel<<<(E + 255) / 256, 256, 0, stream>>>(src, dst, cursor, esrc, E, N);

    const int aggGrid  = (N + 3) / 4;
    const int gemmGrid = (N + 31) / 32;

    // Layer 0: x -> h0 (ReLU)
    sage_aggregate<<<aggGrid, 256, 0, stream>>>(x, offs, esrc, aggr, N);
    sage_gemm<128, true><<<gemmGrid, 256, 0, stream>>>(aggr, x, wl0, wr0, b0, h0, N);

    // Layer 1: h0 -> h1 (ReLU)
    sage_aggregate<<<aggGrid, 256, 0, stream>>>(h0, offs, esrc, aggr, N);
    sage_gemm<128, true><<<gemmGrid, 256, 0, stream>>>(aggr, h0, wl1, wr1, b1, h1, N);

    // Layer 2: h1 -> out (no ReLU)
    sage_aggregate<<<aggGrid, 256, 0, stream>>>(h1, offs, esrc, aggr, N);
    sage_gemm<64, false><<<gemmGrid, 256, 0, stream>>>(aggr, h1, wl2, wr2, b2, out, N);
}

// Round 4
// 546.133 us; speedup vs baseline: 1.3109x; 1.1241x over previous
//
#include <hip/hip_runtime.h>
#include <cstdint>
#include <cstddef>

// ---------------------------------------------------------------------------
// GraphSAGE 3-layer forward, f32.
//   layer: out = act( mean_aggr(h)[dst] @ W_l + b + h @ W_r )
// R4 restructure: matmul and mean-aggregation commute (both linear):
//   out = act( mean_gather(h @ W_l) + (h @ W_r + b) )
// so per layer: ONE fused GEMM produces p = h@Wl and r = h@Wr+b from a single
// LDS staging of h; then a gather kernel does out = act(mean(p[nbrs]) + r).
// Layer 2 gathers 64-wide rows (half the traffic of gathering h1).
// Gather loop unrolled x4 (R3: VALUBusy 13%, one load in flight = latency
// bound; 4 independent slots -> 4 loads in flight).
// NOTE: harness delivers integer inputs as int32 -> edge_index is const int*.
// ---------------------------------------------------------------------------

#define HID 128
#define SCAN_CHUNK 1024   // deg elements per scan block (256 thr x 4)

// ---- small utility --------------------------------------------------------

__global__ __launch_bounds__(256) void zero_i32_kernel(int* __restrict__ p, int n)
{
    int i = blockIdx.x * 256 + threadIdx.x;
    if (i < n) p[i] = 0;
}

// ---- CSR build ------------------------------------------------------------

__global__ __launch_bounds__(256) void deg_hist_kernel(
    const int* __restrict__ dst, int* __restrict__ deg, int E, int n)
{
    int e = blockIdx.x * 256 + threadIdx.x;
    if (e < E) {
        int d = dst[e];
        if (d >= 0 && d < n) atomicAdd(&deg[d], 1);
    }
}

__global__ __launch_bounds__(256) void block_sum_kernel(
    const int* __restrict__ deg, int* __restrict__ partials, int n)
{
    __shared__ int red[256];
    const int base = blockIdx.x * SCAN_CHUNK;
    const int t = threadIdx.x;
    int s = 0;
#pragma unroll
    for (int j = 0; j < 4; ++j) {
        const int idx = base + t * 4 + j;
        s += (idx < n) ? deg[idx] : 0;
    }
    red[t] = s;
    __syncthreads();
    for (int off = 128; off > 0; off >>= 1) {
        if (t < off) red[t] += red[t + off];
        __syncthreads();
    }
    if (t == 0) partials[blockIdx.x] = red[0];
}

__global__ __launch_bounds__(256) void scan_partials_kernel(
    int* __restrict__ partials, int nblk)
{
    __shared__ int buf[256];
    const int t = threadIdx.x;
    const int v = (t < nblk) ? partials[t] : 0;
    buf[t] = v;
    __syncthreads();
    for (int off = 1; off < 256; off <<= 1) {
        const int u = (t >= off) ? buf[t - off] : 0;
        __syncthreads();
        buf[t] += u;
        __syncthreads();
    }
    if (t < nblk) partials[t] = buf[t] - v;   // exclusive
}

__global__ __launch_bounds__(256) void scan_write_kernel(
    const int* __restrict__ deg, const int* __restrict__ partials,
    int* __restrict__ offs, int* __restrict__ cursor, int n, int E)
{
    __shared__ int buf[256];
    const int base = blockIdx.x * SCAN_CHUNK;
    const int t = threadIdx.x;
    int loc[4];
    int s = 0;
#pragma unroll
    for (int j = 0; j < 4; ++j) {
        const int idx = base + t * 4 + j;
        const int d = (idx < n) ? deg[idx] : 0;
        loc[j] = s;
        s += d;
    }
    buf[t] = s;
    __syncthreads();
    for (int off = 1; off < 256; off <<= 1) {
        const int u = (t >= off) ? buf[t - off] : 0;
        __syncthreads();
        buf[t] += u;
        __syncthreads();
    }
    const int tbase = partials[blockIdx.x] + ((t == 0) ? 0 : buf[t - 1]);
#pragma unroll
    for (int j = 0; j < 4; ++j) {
        const int idx = base + t * 4 + j;
        if (idx < n) {
            const int o = tbase + loc[j];
            offs[idx] = o;
            cursor[idx] = o;
        }
    }
    if (blockIdx.x == 0 && t == 0) offs[n] = E;
}

__global__ __launch_bounds__(256) void csr_fill_kernel(
    const int* __restrict__ src, const int* __restrict__ dst,
    int* __restrict__ cursor, int* __restrict__ esrc, int E, int n)
{
    int e = blockIdx.x * 256 + threadIdx.x;
    if (e < E) {
        int d = dst[e];
        int s = src[e];
        if (d >= 0 && d < n && s >= 0 && s < n) {
            int p = atomicAdd(&cursor[d], 1);
            esrc[p] = s;
        }
    }
}

// ---- Fused dual GEMM: p = h @ Wl ; r = h @ Wr + bias ----------------------
// 256 threads, 32-row tile, single LDS stage of h feeds both accumulators.

template <int DOUT>
__global__ __launch_bounds__(256) void sage_dual_gemm(
    const float* __restrict__ h,
    const float* __restrict__ Wl, const float* __restrict__ Wr,
    const float* __restrict__ bias,
    float* __restrict__ p, float* __restrict__ r, int n)
{
    constexpr int K    = HID;
    constexpr int CG   = DOUT / 4;     // column groups (4 cols each)
    constexpr int RG   = 256 / CG;     // row groups
    constexpr int RPT  = 32 / RG;      // rows per thread
    constexpr int ROWS = 32;
    constexpr int LDSS = K + 4;        // padded LDS stride

    __shared__ float sH[ROWS * LDSS];

    const int tx   = threadIdx.x;
    const int row0 = blockIdx.x * ROWS;

    for (int i = tx; i < ROWS * (K / 4); i += 256) {
        const int rr = i / (K / 4);
        const int c4 = i % (K / 4);
        const int row = row0 + rr;
        float4 vh = make_float4(0.f, 0.f, 0.f, 0.f);
        if (row < n) vh = ((const float4*)(h + (size_t)row * K))[c4];
        *(float4*)&sH[rr * LDSS + c4 * 4] = vh;
    }
    __syncthreads();

    const int cg  = tx % CG;
    const int rg  = tx / CG;
    const int col = cg * 4;

    float accp[RPT][4], accr[RPT][4];
#pragma unroll
    for (int i = 0; i < RPT; ++i)
#pragma unroll
        for (int j = 0; j < 4; ++j) { accp[i][j] = 0.f; accr[i][j] = 0.f; }

#pragma unroll 4
    for (int k = 0; k < K; ++k) {
        const float4 wl = *(const float4*)(&Wl[k * DOUT + col]);
        const float4 wr = *(const float4*)(&Wr[k * DOUT + col]);
#pragma unroll
        for (int i = 0; i < RPT; ++i) {
            const float hv = sH[(rg * RPT + i) * LDSS + k];
            accp[i][0] = fmaf(hv, wl.x, accp[i][0]);
            accp[i][1] = fmaf(hv, wl.y, accp[i][1]);
            accp[i][2] = fmaf(hv, wl.z, accp[i][2]);
            accp[i][3] = fmaf(hv, wl.w, accp[i][3]);
            accr[i][0] = fmaf(hv, wr.x, accr[i][0]);
            accr[i][1] = fmaf(hv, wr.y, accr[i][1]);
            accr[i][2] = fmaf(hv, wr.z, accr[i][2]);
            accr[i][3] = fmaf(hv, wr.w, accr[i][3]);
        }
    }

    const float4 bv = *(const float4*)(&bias[col]);
#pragma unroll
    for (int i = 0; i < RPT; ++i) {
        const int row = row0 + rg * RPT + i;
        if (row < n) {
            float4 op, orr;
            op.x = accp[i][0]; op.y = accp[i][1]; op.z = accp[i][2]; op.w = accp[i][3];
            orr.x = accr[i][0] + bv.x;
            orr.y = accr[i][1] + bv.y;
            orr.z = accr[i][2] + bv.z;
            orr.w = accr[i][3] + bv.w;
            *(float4*)(&p[(size_t)row * DOUT + col]) = op;
            *(float4*)(&r[(size_t)row * DOUT + col]) = orr;
        }
    }
}

// ---- Post-aggregation: out = act( mean(p[nbrs]) + r ) ---------------------
// One wave per dst node. DOUT=128: lane owns float2. DOUT=64: lane owns float.
// Neighbor loop unrolled x4 -> 4 independent gathers in flight.

template <int DOUT, bool RELU>
__global__ __launch_bounds__(256) void sage_post_aggregate(
    const float* __restrict__ p, const float* __restrict__ r,
    const int* __restrict__ offs, const int* __restrict__ esrc,
    float* __restrict__ out, int n)
{
    const int wid  = threadIdx.x >> 6;
    const int lane = threadIdx.x & 63;
    const int node = blockIdx.x * 4 + wid;
    if (node >= n) return;
    const int beg = offs[node];
    const int end = offs[node + 1];
    const float inv = 1.0f / fmaxf((float)(end - beg), 1.0f);

    if constexpr (DOUT == 128) {
        float2 a0 = {0.f, 0.f}, a1 = {0.f, 0.f}, a2 = {0.f, 0.f}, a3 = {0.f, 0.f};
        int e = beg;
        for (; e + 4 <= end; e += 4) {
            const int s0 = esrc[e], s1 = esrc[e + 1], s2 = esrc[e + 2], s3 = esrc[e + 3];
            const float2 v0 = *(const float2*)(&p[(size_t)s0 * DOUT + lane * 2]);
            const float2 v1 = *(const float2*)(&p[(size_t)s1 * DOUT + lane * 2]);
            const float2 v2 = *(const float2*)(&p[(size_t)s2 * DOUT + lane * 2]);
            const float2 v3 = *(const float2*)(&p[(size_t)s3 * DOUT + lane * 2]);
            a0.x += v0.x; a0.y += v0.y;
            a1.x += v1.x; a1.y += v1.y;
            a2.x += v2.x; a2.y += v2.y;
            a3.x += v3.x; a3.y += v3.y;
        }
        for (; e < end; ++e) {
            const int s = esrc[e];
            const float2 v = *(const float2*)(&p[(size_t)s * DOUT + lane * 2]);
            a0.x += v.x; a0.y += v.y;
        }
        const float2 rv = *(const float2*)(&r[(size_t)node * DOUT + lane * 2]);
        float ox = (a0.x + a1.x + a2.x + a3.x) * inv + rv.x;
        float oy = (a0.y + a1.y + a2.y + a3.y) * inv + rv.y;
        if (RELU) { ox = fmaxf(ox, 0.f); oy = fmaxf(oy, 0.f); }
        float2 o; o.x = ox; o.y = oy;
        *(float2*)(&out[(size_t)node * DOUT + lane * 2]) = o;
    } else {
        float a0 = 0.f, a1 = 0.f, a2 = 0.f, a3 = 0.f;
        int e = beg;
        for (; e + 4 <= end; e += 4) {
            const int s0 = esrc[e], s1 = esrc[e + 1], s2 = esrc[e + 2], s3 = esrc[e + 3];
            a0 += p[(size_t)s0 * DOUT + lane];
            a1 += p[(size_t)s1 * DOUT + lane];
            a2 += p[(size_t)s2 * DOUT + lane];
            a3 += p[(size_t)s3 * DOUT + lane];
        }
        for (; e < end; ++e) a0 += p[(size_t)esrc[e] * DOUT + lane];
        float o = (a0 + a1 + a2 + a3) * inv + r[(size_t)node * DOUT + lane];
        if (RELU) o = fmaxf(o, 0.f);
        out[(size_t)node * DOUT + lane] = o;
    }
}

// ---------------------------------------------------------------------------

static inline size_t align_up(size_t v, size_t a) { return (v + a - 1) & ~(a - 1); }

extern "C" void kernel_launch(void* const* d_in, const int* in_sizes, int n_in,
                              void* d_out, int out_size, void* d_ws, size_t ws_size,
                              hipStream_t stream)
{
    const float* x   = (const float*)d_in[0];
    const int*   ei  = (const int*)d_in[1];      // int32! (harness converts int64)
    const float* wl0 = (const float*)d_in[2];
    const float* b0  = (const float*)d_in[3];
    const float* wr0 = (const float*)d_in[4];
    const float* wl1 = (const float*)d_in[5];
    const float* b1  = (const float*)d_in[6];
    const float* wr1 = (const float*)d_in[7];
    const float* wl2 = (const float*)d_in[8];
    const float* b2  = (const float*)d_in[9];
    const float* wr2 = (const float*)d_in[10];
    float*       out = (float*)d_out;

    const int N = in_sizes[0] / HID;   // 50000
    const int E = in_sizes[1] / 2;     // 800000
    const int* src = ei;
    const int* dst = ei + E;

    // Workspace carve-up (~81 MB; h1 aliases h0's buffer after gemm1 reads it)
    char*  ws  = (char*)d_ws;
    size_t off = 0;
    int* offs     = (int*)(ws + off); off = align_up(off + (size_t)(N + 1) * 4, 256);
    int* cursor   = (int*)(ws + off); off = align_up(off + (size_t)N * 4, 256);
    int* deg      = (int*)(ws + off); off = align_up(off + (size_t)N * 4, 256);
    int* partials = (int*)(ws + off); off = align_up(off + 256 * 4, 256);
    int* esrc     = (int*)(ws + off); off = align_up(off + (size_t)E * 4, 256);
    float* pbuf   = (float*)(ws + off); off = align_up(off + (size_t)N * HID * 4, 256);
    float* rbuf   = (float*)(ws + off); off = align_up(off + (size_t)N * HID * 4, 256);
    float* hbuf   = (float*)(ws + off); off = align_up(off + (size_t)N * HID * 4, 256);
    (void)ws_size; (void)n_in; (void)out_size;

    const int nScanBlk = (N + SCAN_CHUNK - 1) / SCAN_CHUNK;   // 49

    // --- CSR build (reused by all 3 layers) ---
    zero_i32_kernel<<<(N + 255) / 256, 256, 0, stream>>>(deg, N);
    deg_hist_kernel<<<(E + 255) / 256, 256, 0, stream>>>(dst, deg, E, N);
    block_sum_kernel<<<nScanBlk, 256, 0, stream>>>(deg, partials, N);
    scan_partials_kernel<<<1, 256, 0, stream>>>(partials, nScanBlk);
    scan_write_kernel<<<nScanBlk, 256, 0, stream>>>(deg, partials, offs, cursor, N, E);
    csr_fill_kernel<<<(E + 255) / 256, 256, 0, stream>>>(src, dst, cursor, esrc, E, N);

    const int aggGrid  = (N + 3) / 4;
    const int gemmGrid = (N + 31) / 32;

    // Layer 0: x -> hbuf (ReLU)
    sage_dual_gemm<128><<<gemmGrid, 256, 0, stream>>>(x, wl0, wr0, b0, pbuf, rbuf, N);
    sage_post_aggregate<128, true><<<aggGrid, 256, 0, stream>>>(pbuf, rbuf, offs, esrc, hbuf, N);

    // Layer 1: hbuf -> hbuf (ReLU). gemm reads hbuf before aggregate rewrites it.
    sage_dual_gemm<128><<<gemmGrid, 256, 0, stream>>>(hbuf, wl1, wr1, b1, pbuf, rbuf, N);
    sage_post_aggregate<128, true><<<aggGrid, 256, 0, stream>>>(pbuf, rbuf, offs, esrc, hbuf, N);

    // Layer 2: hbuf -> out (no ReLU), 64-wide gather.
    sage_dual_gemm<64><<<gemmGrid, 256, 0, stream>>>(hbuf, wl2, wr2, b2, pbuf, rbuf, N);
    sage_post_aggregate<64, false><<<aggGrid, 256, 0, stream>>>(pbuf, rbuf, offs, esrc, out, N);
}

// Round 5
// 471.347 us; speedup vs baseline: 1.5188x; 1.1587x over previous
//
#include <hip/hip_runtime.h>
#include <cstdint>
#include <cstddef>

// ---------------------------------------------------------------------------
// GraphSAGE 3-layer forward, f32.
//   layer: out = act( mean_gather(h @ W_l) + (h @ W_r + b) )   (linearity swap)
// R5: GEMM rewritten as LDS-tiled 64x64x64 (R4: W re-loaded from global every
// k-step -> latency-bound, VALUBusy 21%). Both H and W tiles in LDS (32 KB),
// 4x4 register tile/thread, sH XOR-swizzled (k ^ (row&7)<<2) for conflict-free
// broadcast reads. blockIdx.y picks Wl/Wr half; bias fused on r-half.
// NOTE: harness delivers integer inputs as int32 -> edge_index is const int*.
// ---------------------------------------------------------------------------

#define HID 128
#define SCAN_CHUNK 1024   // deg elements per scan block (256 thr x 4)

// ---- small utility --------------------------------------------------------

__global__ __launch_bounds__(256) void zero_i32_kernel(int* __restrict__ p, int n)
{
    int i = blockIdx.x * 256 + threadIdx.x;
    if (i < n) p[i] = 0;
}

// ---- CSR build ------------------------------------------------------------

__global__ __launch_bounds__(256) void deg_hist_kernel(
    const int* __restrict__ dst, int* __restrict__ deg, int E, int n)
{
    int e = blockIdx.x * 256 + threadIdx.x;
    if (e < E) {
        int d = dst[e];
        if (d >= 0 && d < n) atomicAdd(&deg[d], 1);
    }
}

__global__ __launch_bounds__(256) void block_sum_kernel(
    const int* __restrict__ deg, int* __restrict__ partials, int n)
{
    __shared__ int red[256];
    const int base = blockIdx.x * SCAN_CHUNK;
    const int t = threadIdx.x;
    int s = 0;
#pragma unroll
    for (int j = 0; j < 4; ++j) {
        const int idx = base + t * 4 + j;
        s += (idx < n) ? deg[idx] : 0;
    }
    red[t] = s;
    __syncthreads();
    for (int off = 128; off > 0; off >>= 1) {
        if (t < off) red[t] += red[t + off];
        __syncthreads();
    }
    if (t == 0) partials[blockIdx.x] = red[0];
}

__global__ __launch_bounds__(256) void scan_partials_kernel(
    int* __restrict__ partials, int nblk)
{
    __shared__ int buf[256];
    const int t = threadIdx.x;
    const int v = (t < nblk) ? partials[t] : 0;
    buf[t] = v;
    __syncthreads();
    for (int off = 1; off < 256; off <<= 1) {
        const int u = (t >= off) ? buf[t - off] : 0;
        __syncthreads();
        buf[t] += u;
        __syncthreads();
    }
    if (t < nblk) partials[t] = buf[t] - v;   // exclusive
}

__global__ __launch_bounds__(256) void scan_write_kernel(
    const int* __restrict__ deg, const int* __restrict__ partials,
    int* __restrict__ offs, int* __restrict__ cursor, int n, int E)
{
    __shared__ int buf[256];
    const int base = blockIdx.x * SCAN_CHUNK;
    const int t = threadIdx.x;
    int loc[4];
    int s = 0;
#pragma unroll
    for (int j = 0; j < 4; ++j) {
        const int idx = base + t * 4 + j;
        const int d = (idx < n) ? deg[idx] : 0;
        loc[j] = s;
        s += d;
    }
    buf[t] = s;
    __syncthreads();
    for (int off = 1; off < 256; off <<= 1) {
        const int u = (t >= off) ? buf[t - off] : 0;
        __syncthreads();
        buf[t] += u;
        __syncthreads();
    }
    const int tbase = partials[blockIdx.x] + ((t == 0) ? 0 : buf[t - 1]);
#pragma unroll
    for (int j = 0; j < 4; ++j) {
        const int idx = base + t * 4 + j;
        if (idx < n) {
            const int o = tbase + loc[j];
            offs[idx] = o;
            cursor[idx] = o;
        }
    }
    if (blockIdx.x == 0 && t == 0) offs[n] = E;
}

__global__ __launch_bounds__(256) void csr_fill_kernel(
    const int* __restrict__ src, const int* __restrict__ dst,
    int* __restrict__ cursor, int* __restrict__ esrc, int E, int n)
{
    int e = blockIdx.x * 256 + threadIdx.x;
    if (e < E) {
        int d = dst[e];
        int s = src[e];
        if (d >= 0 && d < n && s >= 0 && s < n) {
            int p = atomicAdd(&cursor[d], 1);
            esrc[p] = s;
        }
    }
}

// ---- Fused dual GEMM, LDS-tiled 64x64x64 ----------------------------------
// grid = (ceil(n/64), 2*DOUT/64). blockIdx.y < DOUT/64 -> p half (Wl),
// else r half (Wr, +bias). 256 threads, 4 rows x 4 cols each.

template <int DOUT>
__global__ __launch_bounds__(256) void sage_dual_gemm(
    const float* __restrict__ h,
    const float* __restrict__ Wl, const float* __restrict__ Wr,
    const float* __restrict__ bias,
    float* __restrict__ p, float* __restrict__ r, int n)
{
    constexpr int K  = HID;
    constexpr int BM = 64, BN = 64, BK = 64;
    constexpr int halfBlocks = DOUT / BN;

    __shared__ float sH[BM * BK];   // [row][k ^ ((row&7)<<2)]
    __shared__ float sW[BK * BN];   // [k][c]

    const int tx   = threadIdx.x;
    const int row0 = blockIdx.x * BM;
    const bool isR = (int)blockIdx.y >= halfBlocks;
    const float* __restrict__ W = isR ? Wr : Wl;
    const int cbase = ((int)blockIdx.y - (isR ? halfBlocks : 0)) * BN;
    float* __restrict__ outp = isR ? r : p;

    const int cg = tx & 15;    // col group: cols cg*4 .. cg*4+3
    const int rg = tx >> 4;    // row group: rows rg*4 .. rg*4+3

    float acc[4][4];
#pragma unroll
    for (int i = 0; i < 4; ++i)
#pragma unroll
        for (int j = 0; j < 4; ++j) acc[i][j] = 0.f;

    for (int kk = 0; kk < K; kk += BK) {
        // stage H tile: 64 rows x 64 k (1024 float4, 4 per thread), swizzled
#pragma unroll
        for (int j = 0; j < 4; ++j) {
            const int i  = tx + j * 256;
            const int rw = i >> 4;
            const int c4 = (i & 15) * 4;
            const int row = row0 + rw;
            float4 v = make_float4(0.f, 0.f, 0.f, 0.f);
            if (row < n) v = *(const float4*)(&h[(size_t)row * K + kk + c4]);
            *(float4*)&sH[rw * BK + (c4 ^ ((rw & 7) << 2))] = v;
        }
        // stage W tile: 64 k x 64 c (coalesced, no transpose)
#pragma unroll
        for (int j = 0; j < 4; ++j) {
            const int i  = tx + j * 256;
            const int kw = i >> 4;
            const int c4 = (i & 15) * 4;
            const float4 v = *(const float4*)(&W[(size_t)(kk + kw) * DOUT + cbase + c4]);
            *(float4*)&sW[kw * BN + c4] = v;
        }
        __syncthreads();

#pragma unroll 4
        for (int k0 = 0; k0 < BK; k0 += 4) {
            const float4 wv0 = *(const float4*)&sW[(k0 + 0) * BN + cg * 4];
            const float4 wv1 = *(const float4*)&sW[(k0 + 1) * BN + cg * 4];
            const float4 wv2 = *(const float4*)&sW[(k0 + 2) * BN + cg * 4];
            const float4 wv3 = *(const float4*)&sW[(k0 + 3) * BN + cg * 4];
            float4 hv[4];
#pragma unroll
            for (int i = 0; i < 4; ++i) {
                const int rw = rg * 4 + i;
                hv[i] = *(const float4*)&sH[rw * BK + (k0 ^ ((rw & 7) << 2))];
            }
            // u=0 (hv.x, wv0)
#pragma unroll
            for (int i = 0; i < 4; ++i) {
                acc[i][0] = fmaf(hv[i].x, wv0.x, acc[i][0]);
                acc[i][1] = fmaf(hv[i].x, wv0.y, acc[i][1]);
                acc[i][2] = fmaf(hv[i].x, wv0.z, acc[i][2]);
                acc[i][3] = fmaf(hv[i].x, wv0.w, acc[i][3]);
            }
            // u=1
#pragma unroll
            for (int i = 0; i < 4; ++i) {
                acc[i][0] = fmaf(hv[i].y, wv1.x, acc[i][0]);
                acc[i][1] = fmaf(hv[i].y, wv1.y, acc[i][1]);
                acc[i][2] = fmaf(hv[i].y, wv1.z, acc[i][2]);
                acc[i][3] = fmaf(hv[i].y, wv1.w, acc[i][3]);
            }
            // u=2
#pragma unroll
            for (int i = 0; i < 4; ++i) {
                acc[i][0] = fmaf(hv[i].z, wv2.x, acc[i][0]);
                acc[i][1] = fmaf(hv[i].z, wv2.y, acc[i][1]);
                acc[i][2] = fmaf(hv[i].z, wv2.z, acc[i][2]);
                acc[i][3] = fmaf(hv[i].z, wv2.w, acc[i][3]);
            }
            // u=3
#pragma unroll
            for (int i = 0; i < 4; ++i) {
                acc[i][0] = fmaf(hv[i].w, wv3.x, acc[i][0]);
                acc[i][1] = fmaf(hv[i].w, wv3.y, acc[i][1]);
                acc[i][2] = fmaf(hv[i].w, wv3.z, acc[i][2]);
                acc[i][3] = fmaf(hv[i].w, wv3.w, acc[i][3]);
            }
        }
        __syncthreads();
    }

    float4 bv = make_float4(0.f, 0.f, 0.f, 0.f);
    if (isR) bv = *(const float4*)(&bias[cbase + cg * 4]);
#pragma unroll
    for (int i = 0; i < 4; ++i) {
        const int row = row0 + rg * 4 + i;
        if (row < n) {
            float4 o;
            o.x = acc[i][0] + bv.x;
            o.y = acc[i][1] + bv.y;
            o.z = acc[i][2] + bv.z;
            o.w = acc[i][3] + bv.w;
            *(float4*)(&outp[(size_t)row * DOUT + cbase + cg * 4]) = o;
        }
    }
}

// ---- Post-aggregation: out = act( mean(p[nbrs]) + r ) ---------------------
// One wave per dst node; neighbor loop unrolled x4 (4 gathers in flight).

template <int DOUT, bool RELU>
__global__ __launch_bounds__(256) void sage_post_aggregate(
    const float* __restrict__ p, const float* __restrict__ r,
    const int* __restrict__ offs, const int* __restrict__ esrc,
    float* __restrict__ out, int n)
{
    const int wid  = threadIdx.x >> 6;
    const int lane = threadIdx.x & 63;
    const int node = blockIdx.x * 4 + wid;
    if (node >= n) return;
    const int beg = offs[node];
    const int end = offs[node + 1];
    const float inv = 1.0f / fmaxf((float)(end - beg), 1.0f);

    if constexpr (DOUT == 128) {
        float2 a0 = {0.f, 0.f}, a1 = {0.f, 0.f}, a2 = {0.f, 0.f}, a3 = {0.f, 0.f};
        int e = beg;
        for (; e + 4 <= end; e += 4) {
            const int s0 = esrc[e], s1 = esrc[e + 1], s2 = esrc[e + 2], s3 = esrc[e + 3];
            const float2 v0 = *(const float2*)(&p[(size_t)s0 * DOUT + lane * 2]);
            const float2 v1 = *(const float2*)(&p[(size_t)s1 * DOUT + lane * 2]);
            const float2 v2 = *(const float2*)(&p[(size_t)s2 * DOUT + lane * 2]);
            const float2 v3 = *(const float2*)(&p[(size_t)s3 * DOUT + lane * 2]);
            a0.x += v0.x; a0.y += v0.y;
            a1.x += v1.x; a1.y += v1.y;
            a2.x += v2.x; a2.y += v2.y;
            a3.x += v3.x; a3.y += v3.y;
        }
        for (; e < end; ++e) {
            const int s = esrc[e];
            const float2 v = *(const float2*)(&p[(size_t)s * DOUT + lane * 2]);
            a0.x += v.x; a0.y += v.y;
        }
        const float2 rv = *(const float2*)(&r[(size_t)node * DOUT + lane * 2]);
        float ox = (a0.x + a1.x + a2.x + a3.x) * inv + rv.x;
        float oy = (a0.y + a1.y + a2.y + a3.y) * inv + rv.y;
        if (RELU) { ox = fmaxf(ox, 0.f); oy = fmaxf(oy, 0.f); }
        float2 o; o.x = ox; o.y = oy;
        *(float2*)(&out[(size_t)node * DOUT + lane * 2]) = o;
    } else {
        float a0 = 0.f, a1 = 0.f, a2 = 0.f, a3 = 0.f;
        int e = beg;
        for (; e + 4 <= end; e += 4) {
            const int s0 = esrc[e], s1 = esrc[e + 1], s2 = esrc[e + 2], s3 = esrc[e + 3];
            a0 += p[(size_t)s0 * DOUT + lane];
            a1 += p[(size_t)s1 * DOUT + lane];
            a2 += p[(size_t)s2 * DOUT + lane];
            a3 += p[(size_t)s3 * DOUT + lane];
        }
        for (; e < end; ++e) a0 += p[(size_t)esrc[e] * DOUT + lane];
        float o = (a0 + a1 + a2 + a3) * inv + r[(size_t)node * DOUT + lane];
        if (RELU) o = fmaxf(o, 0.f);
        out[(size_t)node * DOUT + lane] = o;
    }
}

// ---------------------------------------------------------------------------

static inline size_t align_up(size_t v, size_t a) { return (v + a - 1) & ~(a - 1); }

extern "C" void kernel_launch(void* const* d_in, const int* in_sizes, int n_in,
                              void* d_out, int out_size, void* d_ws, size_t ws_size,
                              hipStream_t stream)
{
    const float* x   = (const float*)d_in[0];
    const int*   ei  = (const int*)d_in[1];      // int32! (harness converts int64)
    const float* wl0 = (const float*)d_in[2];
    const float* b0  = (const float*)d_in[3];
    const float* wr0 = (const float*)d_in[4];
    const float* wl1 = (const float*)d_in[5];
    const float* b1  = (const float*)d_in[6];
    const float* wr1 = (const float*)d_in[7];
    const float* wl2 = (const float*)d_in[8];
    const float* b2  = (const float*)d_in[9];
    const float* wr2 = (const float*)d_in[10];
    float*       out = (float*)d_out;

    const int N = in_sizes[0] / HID;   // 50000
    const int E = in_sizes[1] / 2;     // 800000
    const int* src = ei;
    const int* dst = ei + E;

    // Workspace carve-up (~81 MB)
    char*  ws  = (char*)d_ws;
    size_t off = 0;
    int* offs     = (int*)(ws + off); off = align_up(off + (size_t)(N + 1) * 4, 256);
    int* cursor   = (int*)(ws + off); off = align_up(off + (size_t)N * 4, 256);
    int* deg      = (int*)(ws + off); off = align_up(off + (size_t)N * 4, 256);
    int* partials = (int*)(ws + off); off = align_up(off + 256 * 4, 256);
    int* esrc     = (int*)(ws + off); off = align_up(off + (size_t)E * 4, 256);
    float* pbuf   = (float*)(ws + off); off = align_up(off + (size_t)N * HID * 4, 256);
    float* rbuf   = (float*)(ws + off); off = align_up(off + (size_t)N * HID * 4, 256);
    float* hbuf   = (float*)(ws + off); off = align_up(off + (size_t)N * HID * 4, 256);
    (void)ws_size; (void)n_in; (void)out_size;

    const int nScanBlk = (N + SCAN_CHUNK - 1) / SCAN_CHUNK;   // 49

    // --- CSR build (reused by all 3 layers) ---
    zero_i32_kernel<<<(N + 255) / 256, 256, 0, stream>>>(deg, N);
    deg_hist_kernel<<<(E + 255) / 256, 256, 0, stream>>>(dst, deg, E, N);
    block_sum_kernel<<<nScanBlk, 256, 0, stream>>>(deg, partials, N);
    scan_partials_kernel<<<1, 256, 0, stream>>>(partials, nScanBlk);
    scan_write_kernel<<<nScanBlk, 256, 0, stream>>>(deg, partials, offs, cursor, N, E);
    csr_fill_kernel<<<(E + 255) / 256, 256, 0, stream>>>(src, dst, cursor, esrc, E, N);

    const int aggGrid = (N + 3) / 4;
    const int rowBlk  = (N + 63) / 64;
    const dim3 gemmGrid128(rowBlk, 4);   // 2*128/64
    const dim3 gemmGrid64(rowBlk, 2);    // 2*64/64

    // Layer 0: x -> hbuf (ReLU)
    sage_dual_gemm<128><<<gemmGrid128, 256, 0, stream>>>(x, wl0, wr0, b0, pbuf, rbuf, N);
    sage_post_aggregate<128, true><<<aggGrid, 256, 0, stream>>>(pbuf, rbuf, offs, esrc, hbuf, N);

    // Layer 1: hbuf -> hbuf (ReLU)
    sage_dual_gemm<128><<<gemmGrid128, 256, 0, stream>>>(hbuf, wl1, wr1, b1, pbuf, rbuf, N);
    sage_post_aggregate<128, true><<<aggGrid, 256, 0, stream>>>(pbuf, rbuf, offs, esrc, hbuf, N);

    // Layer 2: hbuf -> out (no ReLU), 64-wide gather
    sage_dual_gemm<64><<<gemmGrid64, 256, 0, stream>>>(hbuf, wl2, wr2, b2, pbuf, rbuf, N);
    sage_post_aggregate<64, false><<<aggGrid, 256, 0, stream>>>(pbuf, rbuf, offs, esrc, out, N);
}

// Round 6
// 411.321 us; speedup vs baseline: 1.7405x; 1.1459x over previous
//
#include <hip/hip_runtime.h>
#include <cstdint>
#include <cstddef>

// ---------------------------------------------------------------------------
// GraphSAGE 3-layer forward, f32 compute.
//   layer: out = act( mean_gather(h @ W_l) + (h @ W_r + b) )   (linearity swap)
// R6: gather is BW-bound (R5: 188 MB fetch @ 3.7 TB/s, 54% L2 miss on the
// random 512B row gathers). Store p = h@Wl as bf16 (half the gathered bytes);
// accumulate in f32; r (self path) stays f32 -> only the mean term is rounded.
// Gather loop: predicated x8 unroll (fma by 0/1 weight) = 8 loads in flight,
// no serial tail.
// NOTE: harness delivers integer inputs as int32 -> edge_index is const int*.
// ---------------------------------------------------------------------------

#define HID 128
#define SCAN_CHUNK 1024   // deg elements per scan block (256 thr x 4)

// ---- bf16 helpers (manual, RNE) -------------------------------------------

__device__ __forceinline__ unsigned short f32_to_bf16(float f)
{
    union { float f; unsigned int i; } c; c.f = f;
    const unsigned int x = c.i;
    const unsigned int r = x + 0x7fffu + ((x >> 16) & 1u);   // round-nearest-even
    return (unsigned short)(r >> 16);
}

// ---- small utility --------------------------------------------------------

__global__ __launch_bounds__(256) void zero_i32_kernel(int* __restrict__ p, int n)
{
    int i = blockIdx.x * 256 + threadIdx.x;
    if (i < n) p[i] = 0;
}

// ---- CSR build ------------------------------------------------------------

__global__ __launch_bounds__(256) void deg_hist_kernel(
    const int* __restrict__ dst, int* __restrict__ deg, int E, int n)
{
    int e = blockIdx.x * 256 + threadIdx.x;
    if (e < E) {
        int d = dst[e];
        if (d >= 0 && d < n) atomicAdd(&deg[d], 1);
    }
}

__global__ __launch_bounds__(256) void block_sum_kernel(
    const int* __restrict__ deg, int* __restrict__ partials, int n)
{
    __shared__ int red[256];
    const int base = blockIdx.x * SCAN_CHUNK;
    const int t = threadIdx.x;
    int s = 0;
#pragma unroll
    for (int j = 0; j < 4; ++j) {
        const int idx = base + t * 4 + j;
        s += (idx < n) ? deg[idx] : 0;
    }
    red[t] = s;
    __syncthreads();
    for (int off = 128; off > 0; off >>= 1) {
        if (t < off) red[t] += red[t + off];
        __syncthreads();
    }
    if (t == 0) partials[blockIdx.x] = red[0];
}

__global__ __launch_bounds__(256) void scan_partials_kernel(
    int* __restrict__ partials, int nblk)
{
    __shared__ int buf[256];
    const int t = threadIdx.x;
    const int v = (t < nblk) ? partials[t] : 0;
    buf[t] = v;
    __syncthreads();
    for (int off = 1; off < 256; off <<= 1) {
        const int u = (t >= off) ? buf[t - off] : 0;
        __syncthreads();
        buf[t] += u;
        __syncthreads();
    }
    if (t < nblk) partials[t] = buf[t] - v;   // exclusive
}

__global__ __launch_bounds__(256) void scan_write_kernel(
    const int* __restrict__ deg, const int* __restrict__ partials,
    int* __restrict__ offs, int* __restrict__ cursor, int n, int E)
{
    __shared__ int buf[256];
    const int base = blockIdx.x * SCAN_CHUNK;
    const int t = threadIdx.x;
    int loc[4];
    int s = 0;
#pragma unroll
    for (int j = 0; j < 4; ++j) {
        const int idx = base + t * 4 + j;
        const int d = (idx < n) ? deg[idx] : 0;
        loc[j] = s;
        s += d;
    }
    buf[t] = s;
    __syncthreads();
    for (int off = 1; off < 256; off <<= 1) {
        const int u = (t >= off) ? buf[t - off] : 0;
        __syncthreads();
        buf[t] += u;
        __syncthreads();
    }
    const int tbase = partials[blockIdx.x] + ((t == 0) ? 0 : buf[t - 1]);
#pragma unroll
    for (int j = 0; j < 4; ++j) {
        const int idx = base + t * 4 + j;
        if (idx < n) {
            const int o = tbase + loc[j];
            offs[idx] = o;
            cursor[idx] = o;
        }
    }
    if (blockIdx.x == 0 && t == 0) offs[n] = E;
}

__global__ __launch_bounds__(256) void csr_fill_kernel(
    const int* __restrict__ src, const int* __restrict__ dst,
    int* __restrict__ cursor, int* __restrict__ esrc, int E, int n)
{
    int e = blockIdx.x * 256 + threadIdx.x;
    if (e < E) {
        int d = dst[e];
        int s = src[e];
        if (d >= 0 && d < n && s >= 0 && s < n) {
            int p = atomicAdd(&cursor[d], 1);
            esrc[p] = s;
        }
    }
}

// ---- Fused dual GEMM, LDS-tiled 64x64x64 ----------------------------------
// grid = (ceil(n/64), 2*DOUT/64). blockIdx.y < DOUT/64 -> p half (Wl, bf16
// output), else r half (Wr, +bias, f32 output). 256 thr, 4x4 regs each.

template <int DOUT>
__global__ __launch_bounds__(256) void sage_dual_gemm(
    const float* __restrict__ h,
    const float* __restrict__ Wl, const float* __restrict__ Wr,
    const float* __restrict__ bias,
    unsigned short* __restrict__ p, float* __restrict__ r, int n)
{
    constexpr int K  = HID;
    constexpr int BM = 64, BN = 64, BK = 64;
    constexpr int halfBlocks = DOUT / BN;

    __shared__ float sH[BM * BK];   // [row][k ^ ((row&7)<<2)]
    __shared__ float sW[BK * BN];   // [k][c]

    const int tx   = threadIdx.x;
    const int row0 = blockIdx.x * BM;
    const bool isR = (int)blockIdx.y >= halfBlocks;
    const float* __restrict__ W = isR ? Wr : Wl;
    const int cbase = ((int)blockIdx.y - (isR ? halfBlocks : 0)) * BN;

    const int cg = tx & 15;    // col group: cols cg*4 .. cg*4+3
    const int rg = tx >> 4;    // row group: rows rg*4 .. rg*4+3

    float acc[4][4];
#pragma unroll
    for (int i = 0; i < 4; ++i)
#pragma unroll
        for (int j = 0; j < 4; ++j) acc[i][j] = 0.f;

    for (int kk = 0; kk < K; kk += BK) {
        // stage H tile: 64 rows x 64 k (1024 float4, 4 per thread), swizzled
#pragma unroll
        for (int j = 0; j < 4; ++j) {
            const int i  = tx + j * 256;
            const int rw = i >> 4;
            const int c4 = (i & 15) * 4;
            const int row = row0 + rw;
            float4 v = make_float4(0.f, 0.f, 0.f, 0.f);
            if (row < n) v = *(const float4*)(&h[(size_t)row * K + kk + c4]);
            *(float4*)&sH[rw * BK + (c4 ^ ((rw & 7) << 2))] = v;
        }
        // stage W tile: 64 k x 64 c (coalesced, no transpose)
#pragma unroll
        for (int j = 0; j < 4; ++j) {
            const int i  = tx + j * 256;
            const int kw = i >> 4;
            const int c4 = (i & 15) * 4;
            const float4 v = *(const float4*)(&W[(size_t)(kk + kw) * DOUT + cbase + c4]);
            *(float4*)&sW[kw * BN + c4] = v;
        }
        __syncthreads();

#pragma unroll 4
        for (int k0 = 0; k0 < BK; k0 += 4) {
            const float4 wv0 = *(const float4*)&sW[(k0 + 0) * BN + cg * 4];
            const float4 wv1 = *(const float4*)&sW[(k0 + 1) * BN + cg * 4];
            const float4 wv2 = *(const float4*)&sW[(k0 + 2) * BN + cg * 4];
            const float4 wv3 = *(const float4*)&sW[(k0 + 3) * BN + cg * 4];
            float4 hv[4];
#pragma unroll
            for (int i = 0; i < 4; ++i) {
                const int rw = rg * 4 + i;
                hv[i] = *(const float4*)&sH[rw * BK + (k0 ^ ((rw & 7) << 2))];
            }
#pragma unroll
            for (int i = 0; i < 4; ++i) {
                acc[i][0] = fmaf(hv[i].x, wv0.x, acc[i][0]);
                acc[i][1] = fmaf(hv[i].x, wv0.y, acc[i][1]);
                acc[i][2] = fmaf(hv[i].x, wv0.z, acc[i][2]);
                acc[i][3] = fmaf(hv[i].x, wv0.w, acc[i][3]);
            }
#pragma unroll
            for (int i = 0; i < 4; ++i) {
                acc[i][0] = fmaf(hv[i].y, wv1.x, acc[i][0]);
                acc[i][1] = fmaf(hv[i].y, wv1.y, acc[i][1]);
                acc[i][2] = fmaf(hv[i].y, wv1.z, acc[i][2]);
                acc[i][3] = fmaf(hv[i].y, wv1.w, acc[i][3]);
            }
#pragma unroll
            for (int i = 0; i < 4; ++i) {
                acc[i][0] = fmaf(hv[i].z, wv2.x, acc[i][0]);
                acc[i][1] = fmaf(hv[i].z, wv2.y, acc[i][1]);
                acc[i][2] = fmaf(hv[i].z, wv2.z, acc[i][2]);
                acc[i][3] = fmaf(hv[i].z, wv2.w, acc[i][3]);
            }
#pragma unroll
            for (int i = 0; i < 4; ++i) {
                acc[i][0] = fmaf(hv[i].w, wv3.x, acc[i][0]);
                acc[i][1] = fmaf(hv[i].w, wv3.y, acc[i][1]);
                acc[i][2] = fmaf(hv[i].w, wv3.z, acc[i][2]);
                acc[i][3] = fmaf(hv[i].w, wv3.w, acc[i][3]);
            }
        }
        __syncthreads();
    }

    if (!isR) {
        // p half: convert to bf16, store ushort4 (8 B)
#pragma unroll
        for (int i = 0; i < 4; ++i) {
            const int row = row0 + rg * 4 + i;
            if (row < n) {
                ushort4 o;
                o.x = f32_to_bf16(acc[i][0]);
                o.y = f32_to_bf16(acc[i][1]);
                o.z = f32_to_bf16(acc[i][2]);
                o.w = f32_to_bf16(acc[i][3]);
                *(ushort4*)(&p[(size_t)row * DOUT + cbase + cg * 4]) = o;
            }
        }
    } else {
        const float4 bv = *(const float4*)(&bias[cbase + cg * 4]);
#pragma unroll
        for (int i = 0; i < 4; ++i) {
            const int row = row0 + rg * 4 + i;
            if (row < n) {
                float4 o;
                o.x = acc[i][0] + bv.x;
                o.y = acc[i][1] + bv.y;
                o.z = acc[i][2] + bv.z;
                o.w = acc[i][3] + bv.w;
                *(float4*)(&r[(size_t)row * DOUT + cbase + cg * 4]) = o;
            }
        }
    }
}

// ---- Post-aggregation: out = act( mean(p_bf16[nbrs]) + r ) ----------------
// One wave per dst node. Predicated x8 unroll: index clamped to end-1, fma by
// 0/1 weight -> 8 independent gathers in flight, no serial tail.

template <int DOUT, bool RELU>
__global__ __launch_bounds__(256) void sage_post_aggregate(
    const unsigned short* __restrict__ p, const float* __restrict__ r,
    const int* __restrict__ offs, const int* __restrict__ esrc,
    float* __restrict__ out, int n)
{
    const int wid  = threadIdx.x >> 6;
    const int lane = threadIdx.x & 63;
    const int node = blockIdx.x * 4 + wid;
    if (node >= n) return;
    const int beg = offs[node];
    const int end = offs[node + 1];
    const float inv = 1.0f / fmaxf((float)(end - beg), 1.0f);

    if constexpr (DOUT == 128) {
        float ax[8], ay[8];
#pragma unroll
        for (int j = 0; j < 8; ++j) { ax[j] = 0.f; ay[j] = 0.f; }
        for (int e = beg; e < end; e += 8) {
#pragma unroll
            for (int j = 0; j < 8; ++j) {
                const int idx = e + j;
                const int ee  = min(idx, end - 1);
                const float w = (idx < end) ? 1.0f : 0.0f;
                const int s   = esrc[ee];
                const unsigned int v = *(const unsigned int*)(&p[(size_t)s * DOUT + lane * 2]);
                float fx, fy;
                { union { unsigned int i; float f; } c; c.i = v << 16;          fx = c.f; }
                { union { unsigned int i; float f; } c; c.i = v & 0xffff0000u;  fy = c.f; }
                ax[j] = fmaf(w, fx, ax[j]);
                ay[j] = fmaf(w, fy, ay[j]);
            }
        }
        float sx = ((ax[0] + ax[1]) + (ax[2] + ax[3])) + ((ax[4] + ax[5]) + (ax[6] + ax[7]));
        float sy = ((ay[0] + ay[1]) + (ay[2] + ay[3])) + ((ay[4] + ay[5]) + (ay[6] + ay[7]));
        const float2 rv = *(const float2*)(&r[(size_t)node * DOUT + lane * 2]);
        float ox = sx * inv + rv.x;
        float oy = sy * inv + rv.y;
        if (RELU) { ox = fmaxf(ox, 0.f); oy = fmaxf(oy, 0.f); }
        float2 o; o.x = ox; o.y = oy;
        *(float2*)(&out[(size_t)node * DOUT + lane * 2]) = o;
    } else {
        float a[8];
#pragma unroll
        for (int j = 0; j < 8; ++j) a[j] = 0.f;
        for (int e = beg; e < end; e += 8) {
#pragma unroll
            for (int j = 0; j < 8; ++j) {
                const int idx = e + j;
                const int ee  = min(idx, end - 1);
                const float w = (idx < end) ? 1.0f : 0.0f;
                const int s   = esrc[ee];
                const unsigned short u = p[(size_t)s * DOUT + lane];
                union { unsigned int i; float f; } c; c.i = ((unsigned int)u) << 16;
                a[j] = fmaf(w, c.f, a[j]);
            }
        }
        float sa = ((a[0] + a[1]) + (a[2] + a[3])) + ((a[4] + a[5]) + (a[6] + a[7]));
        float o = sa * inv + r[(size_t)node * DOUT + lane];
        if (RELU) o = fmaxf(o, 0.f);
        out[(size_t)node * DOUT + lane] = o;
    }
}

// ---------------------------------------------------------------------------

static inline size_t align_up(size_t v, size_t a) { return (v + a - 1) & ~(a - 1); }

extern "C" void kernel_launch(void* const* d_in, const int* in_sizes, int n_in,
                              void* d_out, int out_size, void* d_ws, size_t ws_size,
                              hipStream_t stream)
{
    const float* x   = (const float*)d_in[0];
    const int*   ei  = (const int*)d_in[1];      // int32! (harness converts int64)
    const float* wl0 = (const float*)d_in[2];
    const float* b0  = (const float*)d_in[3];
    const float* wr0 = (const float*)d_in[4];
    const float* wl1 = (const float*)d_in[5];
    const float* b1  = (const float*)d_in[6];
    const float* wr1 = (const float*)d_in[7];
    const float* wl2 = (const float*)d_in[8];
    const float* b2  = (const float*)d_in[9];
    const float* wr2 = (const float*)d_in[10];
    float*       out = (float*)d_out;

    const int N = in_sizes[0] / HID;   // 50000
    const int E = in_sizes[1] / 2;     // 800000
    const int* src = ei;
    const int* dst = ei + E;

    // Workspace carve-up (~68 MB)
    char*  ws  = (char*)d_ws;
    size_t off = 0;
    int* offs     = (int*)(ws + off); off = align_up(off + (size_t)(N + 1) * 4, 256);
    int* cursor   = (int*)(ws + off); off = align_up(off + (size_t)N * 4, 256);
    int* deg      = (int*)(ws + off); off = align_up(off + (size_t)N * 4, 256);
    int* partials = (int*)(ws + off); off = align_up(off + 256 * 4, 256);
    int* esrc     = (int*)(ws + off); off = align_up(off + (size_t)E * 4, 256);
    unsigned short* pbuf = (unsigned short*)(ws + off); off = align_up(off + (size_t)N * HID * 2, 256);
    float* rbuf   = (float*)(ws + off); off = align_up(off + (size_t)N * HID * 4, 256);
    float* hbuf   = (float*)(ws + off); off = align_up(off + (size_t)N * HID * 4, 256);
    (void)ws_size; (void)n_in; (void)out_size;

    const int nScanBlk = (N + SCAN_CHUNK - 1) / SCAN_CHUNK;   // 49

    // --- CSR build (reused by all 3 layers) ---
    zero_i32_kernel<<<(N + 255) / 256, 256, 0, stream>>>(deg, N);
    deg_hist_kernel<<<(E + 255) / 256, 256, 0, stream>>>(dst, deg, E, N);
    block_sum_kernel<<<nScanBlk, 256, 0, stream>>>(deg, partials, N);
    scan_partials_kernel<<<1, 256, 0, stream>>>(partials, nScanBlk);
    scan_write_kernel<<<nScanBlk, 256, 0, stream>>>(deg, partials, offs, cursor, N, E);
    csr_fill_kernel<<<(E + 255) / 256, 256, 0, stream>>>(src, dst, cursor, esrc, E, N);

    const int aggGrid = (N + 3) / 4;
    const int rowBlk  = (N + 63) / 64;
    const dim3 gemmGrid128(rowBlk, 4);   // 2*128/64
    const dim3 gemmGrid64(rowBlk, 2);    // 2*64/64

    // Layer 0: x -> hbuf (ReLU)
    sage_dual_gemm<128><<<gemmGrid128, 256, 0, stream>>>(x, wl0, wr0, b0, pbuf, rbuf, N);
    sage_post_aggregate<128, true><<<aggGrid, 256, 0, stream>>>(pbuf, rbuf, offs, esrc, hbuf, N);

    // Layer 1: hbuf -> hbuf (ReLU)
    sage_dual_gemm<128><<<gemmGrid128, 256, 0, stream>>>(hbuf, wl1, wr1, b1, pbuf, rbuf, N);
    sage_post_aggregate<128, true><<<aggGrid, 256, 0, stream>>>(pbuf, rbuf, offs, esrc, hbuf, N);

    // Layer 2: hbuf -> out (no ReLU), 64-wide bf16 gather (128 B/row)
    sage_dual_gemm<64><<<gemmGrid64, 256, 0, stream>>>(hbuf, wl2, wr2, b2, pbuf, rbuf, N);
    sage_post_aggregate<64, false><<<aggGrid, 256, 0, stream>>>(pbuf, rbuf, offs, esrc, out, N);
}